// Round 16
// baseline (180.249 us; speedup 1.0000x reference)
//
#include <hip/hip_runtime.h>
#include <hip/hip_fp16.h>
#include <math.h>

#define N_ 100000
#define E_ 3200000
#define K_ 1024
#define D_ 11
#define NBUCK_ 391            // ceil(N/256) buckets of 256 nodes (by src>>8)
#define CAPB_ 16384           // global slots per bucket (mean fill ~8184)
#define CAP_ 64               // LDS staging slots per bucket (mean fill 32)
#define CAPW_ 65              // padded stride: 65%32==1 -> bank=(b+pos)%32, uniform
#define GB_ 256               // binning blocks (halved drain RMWs per cursor)
#define BT_ 1024              // k_bin block threads (16 waves/CU at 1 block/CU)
#define CHUNK_ 12512          // edges per binning block (mult of 8; 256*12512 >= E)
#define XC_ 32                // xmean partial copies (spread atomic contention)
#define RSEG_ 4096            // ready-edge region size (32 regions, mean fill ~1k)
#define RSTRIDE_ 16           // region counters padded to one 64B line each

static inline size_t align512(size_t x) { return (x + 511) & ~(size_t)511; }

__device__ inline float2 h2f(unsigned int u) {
    __half2 h = *reinterpret_cast<__half2*>(&u);
    return __half22float2(h);
}

// ---- bucket partition: stage whole chunk (CAP bounds it), single drain -----
// bcur holds OFFSETS within bucket (gbuf index = b*CAPB_ + off); init via
// hipMemsetAsync. Single atomic reservation per (block,bucket).
// Node-prep free-ride (R32). R33: xh split into packed xa (16B: f0..7) +
// xb (8B: f8..10 + dis) — gather loads fully consumed, -25% gather bytes.
// pack = (src&255)<<17 | dst
__global__ __launch_bounds__(BT_) void k_bin(const int* __restrict__ src,
                                             const int* __restrict__ dst,
                                             const float* __restrict__ x,
                                             const int* __restrict__ ready,
                                             int* __restrict__ bcur,
                                             int* __restrict__ gbuf,
                                             __half* __restrict__ xa,
                                             __half* __restrict__ xb,
                                             unsigned char* __restrict__ flag,
                                             float* __restrict__ pr_raw,
                                             float* __restrict__ xpart,
                                             int* __restrict__ rcntp) {
    __shared__ int sbuf[NBUCK_ * CAPW_];   // ~101.7 KB, stride 65
    __shared__ int scnt[NBUCK_];
    int t = threadIdx.x;
    for (int b = t; b < NBUCK_; b += BT_) scnt[b] = 0;
    __syncthreads();
    long e0 = (long)blockIdx.x * CHUNK_;
    for (int r = 0; r < CHUNK_; r += BT_ * 8) {
        int off = r + t * 8;
        long i0 = e0 + off;
        if (off < CHUNK_ && i0 + 7 < E_) {   // CHUNK_%8==0: all-or-nothing
            int4 s0 = *(const int4*)(src + i0);
            int4 s1 = *(const int4*)(src + i0 + 4);
            int4 d0 = *(const int4*)(dst + i0);
            int4 d1 = *(const int4*)(dst + i0 + 4);
            int ss[8] = {s0.x, s0.y, s0.z, s0.w, s1.x, s1.y, s1.z, s1.w};
            int dd[8] = {d0.x, d0.y, d0.z, d0.w, d1.x, d1.y, d1.z, d1.w};
#pragma unroll
            for (int q = 0; q < 8; q++) {
                int b = ss[q] >> 8;
                int pack = ((ss[q] & 255) << 17) | dd[q];
                int pos = atomicAdd(&scnt[b], 1);
                if (pos < CAP_) sbuf[b * CAPW_ + pos] = pack;
                else gbuf[b * CAPB_ + atomicAdd(&bcur[b], 1)] = pack;  // ~never
            }
        }
    }
    // node-prep free-ride (no dependency on staging; overlaps drain wait)
    int gid = blockIdx.x * BT_ + t;
    if (gid < N_) {
        __half ha[8], hb[4];
#pragma unroll
        for (int j = 0; j < 8; j++) ha[j] = __float2half_rn(x[(size_t)gid * D_ + j]);
        hb[0] = __float2half_rn(x[(size_t)gid * D_ + 8]);
        hb[1] = __float2half_rn(x[(size_t)gid * D_ + 9]);
        hb[2] = __float2half_rn(x[(size_t)gid * D_ + 10]);
        hb[3] = __float2half_rn(0.f);   // dis slot, overwritten by k_deg
        *(uint4*)(xa + (size_t)gid * 8) = *(uint4*)ha;
        *(uint2*)(xb + (size_t)gid * 4) = *(uint2*)hb;
        pr_raw[gid] = 0.f;
        int lo = 0, hi = K_ - 1, f = 0;
        while (lo <= hi) {
            int mid = (lo + hi) >> 1;
            int v = ready[mid];
            if (v == gid) { f = 1; break; }
            if (v < gid) lo = mid + 1; else hi = mid - 1;
        }
        flag[gid] = (unsigned char)f;
    }
    if (gid < XC_ * 64) xpart[gid] = 0.f;
    if (gid < 32 * RSTRIDE_) rcntp[gid] = 0;
    __syncthreads();
    // single-reservation drain: one atomic per non-empty bucket
    for (int b = t; b < NBUCK_; b += BT_) {
        int c = min(scnt[b], CAP_);
        if (c == 0) continue;
        int off = atomicAdd(&bcur[b], c);
        int g = b * CAPB_ + off;
        int k = 0;
        while (((off + k) & 3) && k < c) { gbuf[g + k] = sbuf[b*CAPW_ + k]; k++; }
        for (; k + 3 < c; k += 4)
            *(int4*)(gbuf + g + k) = make_int4(sbuf[b*CAPW_ + k],
                                               sbuf[b*CAPW_ + k + 1],
                                               sbuf[b*CAPW_ + k + 2],
                                               sbuf[b*CAPW_ + k + 3]);
        for (; k < c; k++) gbuf[g + k] = sbuf[b*CAPW_ + k];
    }
}

// ---- per-bucket FULL degree hist (one 1024-thread block per bucket) --------
// hist[t] is the complete degree of node (b<<8)+t. Slimmed to hist + dis +
// xb dis-slot + ghist handoff (node-prep lives in k_bin).
__global__ __launch_bounds__(1024) void k_deg(const int* __restrict__ bcur,
                                              const int* __restrict__ gbuf,
                                              float* __restrict__ dis,
                                              __half* __restrict__ xb,
                                              int* __restrict__ ghist) {
    __shared__ int hist[256];
    int t = threadIdx.x, b = blockIdx.x;
    if (t < 256) hist[t] = 0;
    __syncthreads();
    int base = b * CAPB_;
    int cnt = min(bcur[b], CAPB_);
    int p = t * 4;
    for (; p + 3 < cnt; p += 4096) {
        int4 v = *(const int4*)(gbuf + base + p);
        atomicAdd(&hist[v.x >> 17], 1);
        atomicAdd(&hist[v.y >> 17], 1);
        atomicAdd(&hist[v.z >> 17], 1);
        atomicAdd(&hist[v.w >> 17], 1);
    }
    if (p < cnt) {   // tail group (<4), exactly one thread's window
        for (int q = p; q < cnt; q++) atomicAdd(&hist[gbuf[base + q] >> 17], 1);
    }
    __syncthreads();
    if (t < 256) {
        ghist[(b << 8) + t] = hist[t];            // handoff to k_agx
        int node = (b << 8) + t;
        if (node < N_) {
            float dv = rsqrtf((float)(hist[t] + 1));
            dis[node] = dv;
            xb[(size_t)node * 4 + 3] = __float2half_rn(dv);
        }
    }
}

// ------- fused k_agx: whole bucket per 1024-thread block ---------------------
// hist from ghist; scan, rescan scatter, 4 threads/node accumulate + quad
// shfl reduce, full node transform. R33: gather reads xa (16B) + xb (8B) —
// every byte consumed.
__global__ __launch_bounds__(1024, 8) void k_agx(
    const int* __restrict__ bcur, const int* __restrict__ gbuf,
    const int* __restrict__ ghist,
    const __half* __restrict__ xa, const __half* __restrict__ xb,
    const float* __restrict__ x,
    const unsigned char* __restrict__ flag,
    const float* __restrict__ W1, const float* __restrict__ b1,
    const float* __restrict__ W2,
    float* __restrict__ hd, float* __restrict__ xpart,
    int* __restrict__ rcntp, int2* __restrict__ redge) {
    __shared__ int sorted[CAPB_];     // 64 KB
    __shared__ int hist[256];
    __shared__ int incl[256];
    __shared__ int offa[256];
    __shared__ int cur[256];
    __shared__ float sW1[D_ * 64];
    __shared__ float sb1[64];
    __shared__ float sW2[75];
    __shared__ float smean[64];
    int t = threadIdx.x, b = blockIdx.x;
    if (t < D_ * 64) sW1[t] = W1[t];
    if (t >= 768 && t < 832) { sb1[t - 768] = b1[t - 768]; smean[t - 768] = 0.f; }
    if (t >= 832 && t < 907) sW2[t - 832] = W2[t - 832];
    if (t < 256) hist[t] = ghist[(b << 8) + t];   // no gbuf re-read for hist
    __syncthreads();
    int base = b * CAPB_;
    int cnt = min(bcur[b], CAPB_);
    // phase 2: inclusive scan over 256 (first 256 threads)
    if (t < 256) incl[t] = hist[t];
    __syncthreads();
    for (int off = 1; off < 256; off <<= 1) {
        int v = 0;
        if (t < 256 && t >= off) v = incl[t - off];
        __syncthreads();
        if (t < 256) incl[t] += v;
        __syncthreads();
    }
    if (t < 256) { int o = incl[t] - hist[t]; offa[t] = o; cur[t] = o; }
    __syncthreads();
    // phase 3: scatter (single gbuf pass)
    for (int idx = t; idx < cnt; idx += 1024) {
        int pk = gbuf[base + idx];
        sorted[atomicAdd(&cur[pk >> 17], 1)] = pk;
    }
    __syncthreads();
    // phase 4: per-node accumulate (4 threads/node) + transform
    int nl = t >> 2, q = t & 3;
    int node = (b << 8) + nl;
    bool valid = node < N_;
    int my_start = offa[nl], my_cnt = hist[nl];
    const uint4* xra = (const uint4*)xa;
    const uint2* xrb = (const uint2*)xb;
    float acc[D_];
#pragma unroll
    for (int j = 0; j < D_; j++) acc[j] = 0.f;
    for (int i = q; i < my_cnt; i += 4) {
        int pack = sorted[my_start + i];
        size_t d = (size_t)(pack & 131071);
        uint4 A = xra[d]; uint2 B = xrb[d];
        float2 f0 = h2f(A.x), f1 = h2f(A.y), f2 = h2f(A.z);
        float2 f3 = h2f(A.w), f4 = h2f(B.x), f5 = h2f(B.y);
        float w = f5.y;   // dis[d]
        acc[0]  = fmaf(w, f0.x, acc[0]);
        acc[1]  = fmaf(w, f0.y, acc[1]);
        acc[2]  = fmaf(w, f1.x, acc[2]);
        acc[3]  = fmaf(w, f1.y, acc[3]);
        acc[4]  = fmaf(w, f2.x, acc[4]);
        acc[5]  = fmaf(w, f2.y, acc[5]);
        acc[6]  = fmaf(w, f3.x, acc[6]);
        acc[7]  = fmaf(w, f3.y, acc[7]);
        acc[8]  = fmaf(w, f4.x, acc[8]);
        acc[9]  = fmaf(w, f4.y, acc[9]);
        acc[10] = fmaf(w, f5.x, acc[10]);
    }
#pragma unroll
    for (int j = 0; j < D_; j++) {
        acc[j] += __shfl_xor(acc[j], 1);
        acc[j] += __shfl_xor(acc[j], 2);
    }
    float hreg[16];
    float h2v = 0.f;
    float di = 0.f;
    if (valid) {
        di = rsqrtf((float)(hist[nl] + 1));   // == dis[node], recomputed
        float xr_[D_], g[D_];
#pragma unroll
        for (int j = 0; j < D_; j++) xr_[j] = x[(size_t)node * D_ + j];
        if (q == 0) {
#pragma unroll
            for (int jj = 0; jj < D_; jj++) h2v = fmaf(xr_[jj], sW2[64 + jj], h2v);
        }
#pragma unroll
        for (int j = 0; j < D_; j++) g[j] = di * (acc[j] + di * xr_[j]);
        int fbase = q << 4;
#pragma unroll
        for (int j = 0; j < 16; j++) {
            int f = fbase + j;
            float a = sb1[f];
#pragma unroll
            for (int jj = 0; jj < D_; jj++) a = fmaf(g[jj], sW1[jj * 64 + f], a);
            float hf = fmaxf(a, 0.f);
            hreg[j] = hf;
            h2v = fmaf(hf, sW2[f], h2v);
        }
    } else {
#pragma unroll
        for (int j = 0; j < 16; j++) hreg[j] = 0.f;
    }
    h2v += __shfl_xor(h2v, 1);
    h2v += __shfl_xor(h2v, 2);
    if (valid && q == 0) hd[node] = di * h2v;  // pre-scaled for conv2

    // smean: reduce each feature across the 16 same-quarter lanes (stride 4)
    int lane = t & 63;
#pragma unroll
    for (int j = 0; j < 16; j++) {
        float v = hreg[j];
        v += __shfl_xor(v, 4);
        v += __shfl_xor(v, 8);
        v += __shfl_xor(v, 16);
        v += __shfl_xor(v, 32);
        if (lane < 4) atomicAdd(&smean[(lane << 4) + j], v);
    }
    __syncthreads();
    if (t < 64) atomicAdd(&xpart[((b & (XC_ - 1)) << 6) + t], smean[t]);

    // ready-edge extraction: quad-cooperative
    if (valid && my_cnt > 0 && flag[node]) {
        int r = b & 31;
        int slot = 0;
        if (q == 0) slot = atomicAdd(&rcntp[r * RSTRIDE_], my_cnt);
        slot = __shfl(slot, lane & ~3);
        int lim = min(my_cnt, max(0, RSEG_ - slot));
        for (int i2 = q; i2 < lim; i2 += 4)
            redge[(r << 12) + slot + i2] =
                make_int2(node, sorted[my_start + i2] & 131071);
    }
}

// ---------------- conv2: process the compact ready-edge list ----------------
__global__ void k_pr(const int* __restrict__ rcntp, const int2* __restrict__ redge,
                     const float* __restrict__ hd, float* __restrict__ pr_raw) {
    int idx = blockIdx.x * blockDim.x + threadIdx.x;
    int r = idx >> 12;            // region
    int off = idx & (RSEG_ - 1);
    if (r < 32 && off < min(rcntp[r * RSTRIDE_], RSEG_)) {
        int2 e = redge[(r << 12) + off];
        atomicAdd(&pr_raw[e.x], hd[e.y]);
    }
}

// ---------------- finalize: logits, prob_nothing, v, softmax ----------------
__global__ __launch_bounds__(1024) void k_final(
    const int* __restrict__ ready, const float* __restrict__ dis,
    const float* __restrict__ hd, const float* __restrict__ pr_raw,
    const float* __restrict__ xpart,
    const float* __restrict__ b2,
    const float* __restrict__ Wd, const float* __restrict__ bd,
    const float* __restrict__ Wv, const float* __restrict__ bv,
    float* __restrict__ out) {
    __shared__ float xm[64];
    __shared__ float red[1024];
    __shared__ float s_max, s_sum, s_pn, s_v;
    int t = threadIdx.x;
    if (t < 64) {
        float s = 0.f;
#pragma unroll
        for (int c = 0; c < XC_; c++) s += xpart[(c << 6) + t];
        xm[t] = s * (1.0f / N_);
    }
    __syncthreads();
    if (t == 0) {
        float pn = bd[0], vv = bv[0];
        for (int f = 0; f < 64; f++) { pn += xm[f] * Wd[f]; vv += xm[f] * Wv[f]; }
        s_pn = pn; s_v = vv;
    }
    int r = ready[t];
    float dr = dis[r];
    float l = dr * (pr_raw[r] + hd[r]) + b2[0];   // dr*Σhd[d] + dr²h2[r] + b2
    __syncthreads();
    float pn = s_pn;
    red[t] = (t == 0) ? fmaxf(l, pn) : l;
    __syncthreads();
    for (int sft = 512; sft > 0; sft >>= 1) {
        if (t < sft) red[t] = fmaxf(red[t], red[t + sft]);
        __syncthreads();
    }
    if (t == 0) s_max = red[0];
    __syncthreads();
    float m = s_max;
    float el = expf(l - m);
    red[t] = el + ((t == 0) ? expf(pn - m) : 0.f);
    __syncthreads();
    for (int sft = 512; sft > 0; sft >>= 1) {
        if (t < sft) red[t] += red[t + sft];
        __syncthreads();
    }
    if (t == 0) s_sum = red[0];
    __syncthreads();
    float inv = 1.0f / s_sum;
    out[t] = el * inv;
    if (t == 0) {
        out[K_] = expf(pn - m) * inv;   // prob_nothing slot
        out[K_ + 1] = s_v;              // v
    }
}

extern "C" void kernel_launch(void* const* d_in, const int* in_sizes, int n_in,
                              void* d_out, int out_size, void* d_ws, size_t ws_size,
                              hipStream_t stream) {
    const float* x    = (const float*)d_in[0];
    const int*   ei   = (const int*)d_in[1];
    const int*   src  = ei;
    const int*   dst  = ei + E_;
    const int*   ready= (const int*)d_in[2];
    const float* W1   = (const float*)d_in[3];
    const float* b1   = (const float*)d_in[4];
    const float* W2   = (const float*)d_in[5];
    const float* b2   = (const float*)d_in[6];
    const float* Wd   = (const float*)d_in[7];
    const float* bd   = (const float*)d_in[8];
    const float* Wv   = (const float*)d_in[9];
    const float* bv   = (const float*)d_in[10];
    float* out = (float*)d_out;

    char* ws = (char*)d_ws;
    size_t o = 0;
    int*   bcur   = (int*)(ws + o);          o += align512(NBUCK_ * sizeof(int));
    int*   rcntp  = (int*)(ws + o);          o += align512(32 * RSTRIDE_ * sizeof(int));
    int*   gbuf   = (int*)(ws + o);          o += align512((size_t)NBUCK_ * CAPB_ * sizeof(int));
    int*   ghist  = (int*)(ws + o);          o += align512((size_t)NBUCK_ * 256 * sizeof(int));
    __half* xa    = (__half*)(ws + o);       o += align512((size_t)N_ * 8 * sizeof(__half));
    __half* xb    = (__half*)(ws + o);       o += align512((size_t)N_ * 4 * sizeof(__half));
    int2*  redge  = (int2*)(ws + o);         o += align512((size_t)32 * RSEG_ * sizeof(int2));
    float* dis    = (float*)(ws + o);        o += align512(N_ * sizeof(float));
    float* hd     = (float*)(ws + o);        o += align512(N_ * sizeof(float));
    float* pr_raw = (float*)(ws + o);        o += align512(N_ * sizeof(float));
    unsigned char* flag = (unsigned char*)(ws + o); o += align512(N_);
    float* xpart  = (float*)(ws + o);        o += align512(XC_ * 64 * sizeof(float));

    const int B = 256;
    int g_pr = (32 * RSEG_) / B;

    hipMemsetAsync(bcur, 0, NBUCK_ * sizeof(int), stream);
    k_bin  <<<GB_, BT_, 0, stream>>>(src, dst, x, ready, bcur, gbuf,
                                     xa, xb, flag, pr_raw, xpart, rcntp);
    k_deg  <<<NBUCK_, 1024, 0, stream>>>(bcur, gbuf, dis, xb, ghist);
    k_agx  <<<NBUCK_, 1024, 0, stream>>>(bcur, gbuf, ghist, xa, xb, x, flag,
                                         W1, b1, W2, hd, xpart, rcntp, redge);
    k_pr   <<<g_pr, B, 0, stream>>>(rcntp, redge, hd, pr_raw);
    k_final<<<1, 1024, 0, stream>>>(ready, dis, hd, pr_raw, xpart,
                                    b2, Wd, bd, Wv, bv, out);
}

// Round 17
// 176.654 us; speedup vs baseline: 1.0204x; 1.0204x over previous
//
#include <hip/hip_runtime.h>
#include <hip/hip_fp16.h>
#include <math.h>

#define N_ 100000
#define E_ 3200000
#define K_ 1024
#define D_ 11
#define NBUCK_ 391            // ceil(N/256) buckets of 256 nodes (by src>>8)
#define CAPB_ 16384           // global slots per bucket (mean fill ~8184)
#define CAP_ 64               // LDS staging slots per bucket (mean fill 32)
#define CAPW_ 65              // padded stride: 65%32==1 -> bank=(b+pos)%32, uniform
#define GB_ 256               // binning blocks (halved drain RMWs per cursor)
#define BT_ 1024              // k_bin block threads (16 waves/CU at 1 block/CU)
#define CHUNK_ 12512          // edges per binning block (mult of 8; 256*12512 >= E)
#define XC_ 32                // xmean partial copies (spread atomic contention)
#define RSEG_ 4096            // ready-edge region size (32 regions, mean fill ~1k)
#define RSTRIDE_ 16           // region counters padded to one 64B line each

static inline size_t align512(size_t x) { return (x + 511) & ~(size_t)511; }

__device__ inline float2 h2f(unsigned int u) {
    __half2 h = *reinterpret_cast<__half2*>(&u);
    return __half22float2(h);
}

// ---- bucket partition: stage whole chunk (CAP bounds it), single drain -----
// bcur holds OFFSETS within bucket (gbuf index = b*CAPB_ + off); init via
// hipMemsetAsync. Single atomic reservation per (block,bucket).
// Node-prep free-ride (R32). R34: xh back to UNIFIED 32B rows — R33's split
// doubled per-edge cache-line touches (latency-bound gather prices lines,
// not bytes). pack = (src&255)<<17 | dst
__global__ __launch_bounds__(BT_) void k_bin(const int* __restrict__ src,
                                             const int* __restrict__ dst,
                                             const float* __restrict__ x,
                                             const int* __restrict__ ready,
                                             int* __restrict__ bcur,
                                             int* __restrict__ gbuf,
                                             __half* __restrict__ xh,
                                             unsigned char* __restrict__ flag,
                                             float* __restrict__ pr_raw,
                                             float* __restrict__ xpart,
                                             int* __restrict__ rcntp) {
    __shared__ int sbuf[NBUCK_ * CAPW_];   // ~101.7 KB, stride 65
    __shared__ int scnt[NBUCK_];
    int t = threadIdx.x;
    for (int b = t; b < NBUCK_; b += BT_) scnt[b] = 0;
    __syncthreads();
    long e0 = (long)blockIdx.x * CHUNK_;
    for (int r = 0; r < CHUNK_; r += BT_ * 8) {
        int off = r + t * 8;
        long i0 = e0 + off;
        if (off < CHUNK_ && i0 + 7 < E_) {   // CHUNK_%8==0: all-or-nothing
            int4 s0 = *(const int4*)(src + i0);
            int4 s1 = *(const int4*)(src + i0 + 4);
            int4 d0 = *(const int4*)(dst + i0);
            int4 d1 = *(const int4*)(dst + i0 + 4);
            int ss[8] = {s0.x, s0.y, s0.z, s0.w, s1.x, s1.y, s1.z, s1.w};
            int dd[8] = {d0.x, d0.y, d0.z, d0.w, d1.x, d1.y, d1.z, d1.w};
#pragma unroll
            for (int q = 0; q < 8; q++) {
                int b = ss[q] >> 8;
                int pack = ((ss[q] & 255) << 17) | dd[q];
                int pos = atomicAdd(&scnt[b], 1);
                if (pos < CAP_) sbuf[b * CAPW_ + pos] = pack;
                else gbuf[b * CAPB_ + atomicAdd(&bcur[b], 1)] = pack;  // ~never
            }
        }
    }
    // node-prep free-ride (no dependency on staging; overlaps drain wait)
    int gid = blockIdx.x * BT_ + t;
    if (gid < N_) {
        __half hh[16];
#pragma unroll
        for (int j = 0; j < D_; j++) hh[j] = __float2half_rn(x[(size_t)gid * D_ + j]);
#pragma unroll
        for (int j = D_; j < 16; j++) hh[j] = __float2half_rn(0.f);
        uint4* dstp = (uint4*)(xh + (size_t)gid * 16);
        dstp[0] = *(uint4*)(hh);
        dstp[1] = *(uint4*)(hh + 8);   // slot 11 overwritten by k_deg (dis)
        pr_raw[gid] = 0.f;
        int lo = 0, hi = K_ - 1, f = 0;
        while (lo <= hi) {
            int mid = (lo + hi) >> 1;
            int v = ready[mid];
            if (v == gid) { f = 1; break; }
            if (v < gid) lo = mid + 1; else hi = mid - 1;
        }
        flag[gid] = (unsigned char)f;
    }
    if (gid < XC_ * 64) xpart[gid] = 0.f;
    if (gid < 32 * RSTRIDE_) rcntp[gid] = 0;
    __syncthreads();
    // single-reservation drain: one atomic per non-empty bucket
    for (int b = t; b < NBUCK_; b += BT_) {
        int c = min(scnt[b], CAP_);
        if (c == 0) continue;
        int off = atomicAdd(&bcur[b], c);
        int g = b * CAPB_ + off;
        int k = 0;
        while (((off + k) & 3) && k < c) { gbuf[g + k] = sbuf[b*CAPW_ + k]; k++; }
        for (; k + 3 < c; k += 4)
            *(int4*)(gbuf + g + k) = make_int4(sbuf[b*CAPW_ + k],
                                               sbuf[b*CAPW_ + k + 1],
                                               sbuf[b*CAPW_ + k + 2],
                                               sbuf[b*CAPW_ + k + 3]);
        for (; k < c; k++) gbuf[g + k] = sbuf[b*CAPW_ + k];
    }
}

// ---- per-bucket FULL degree hist (one 1024-thread block per bucket) --------
// hist[t] is the complete degree of node (b<<8)+t. Slimmed to hist + dis +
// xh slot-11 + ghist handoff (node-prep lives in k_bin).
__global__ __launch_bounds__(1024) void k_deg(const int* __restrict__ bcur,
                                              const int* __restrict__ gbuf,
                                              float* __restrict__ dis,
                                              __half* __restrict__ xh,
                                              int* __restrict__ ghist) {
    __shared__ int hist[256];
    int t = threadIdx.x, b = blockIdx.x;
    if (t < 256) hist[t] = 0;
    __syncthreads();
    int base = b * CAPB_;
    int cnt = min(bcur[b], CAPB_);
    int p = t * 4;
    for (; p + 3 < cnt; p += 4096) {
        int4 v = *(const int4*)(gbuf + base + p);
        atomicAdd(&hist[v.x >> 17], 1);
        atomicAdd(&hist[v.y >> 17], 1);
        atomicAdd(&hist[v.z >> 17], 1);
        atomicAdd(&hist[v.w >> 17], 1);
    }
    if (p < cnt) {   // tail group (<4), exactly one thread's window
        for (int q = p; q < cnt; q++) atomicAdd(&hist[gbuf[base + q] >> 17], 1);
    }
    __syncthreads();
    if (t < 256) {
        ghist[(b << 8) + t] = hist[t];            // handoff to k_agx
        int node = (b << 8) + t;
        if (node < N_) {
            float dv = rsqrtf((float)(hist[t] + 1));
            dis[node] = dv;
            xh[(size_t)node * 16 + 11] = __float2half_rn(dv);
        }
    }
}

// ------- fused k_agx: whole bucket per 1024-thread block ---------------------
// hist from ghist; scan, rescan scatter, 4 threads/node accumulate + quad
// shfl reduce, full node transform. R34: 2-edge ILP batch in the gather loop
// (issue both rows' loads back-to-back -> 2x memory-level parallelism).
__global__ __launch_bounds__(1024, 8) void k_agx(
    const int* __restrict__ bcur, const int* __restrict__ gbuf,
    const int* __restrict__ ghist,
    const __half* __restrict__ xh, const float* __restrict__ x,
    const unsigned char* __restrict__ flag,
    const float* __restrict__ W1, const float* __restrict__ b1,
    const float* __restrict__ W2,
    float* __restrict__ hd, float* __restrict__ xpart,
    int* __restrict__ rcntp, int2* __restrict__ redge) {
    __shared__ int sorted[CAPB_];     // 64 KB
    __shared__ int hist[256];
    __shared__ int incl[256];
    __shared__ int offa[256];
    __shared__ int cur[256];
    __shared__ float sW1[D_ * 64];
    __shared__ float sb1[64];
    __shared__ float sW2[75];
    __shared__ float smean[64];
    int t = threadIdx.x, b = blockIdx.x;
    if (t < D_ * 64) sW1[t] = W1[t];
    if (t >= 768 && t < 832) { sb1[t - 768] = b1[t - 768]; smean[t - 768] = 0.f; }
    if (t >= 832 && t < 907) sW2[t - 832] = W2[t - 832];
    if (t < 256) hist[t] = ghist[(b << 8) + t];   // no gbuf re-read for hist
    __syncthreads();
    int base = b * CAPB_;
    int cnt = min(bcur[b], CAPB_);
    // phase 2: inclusive scan over 256 (first 256 threads)
    if (t < 256) incl[t] = hist[t];
    __syncthreads();
    for (int off = 1; off < 256; off <<= 1) {
        int v = 0;
        if (t < 256 && t >= off) v = incl[t - off];
        __syncthreads();
        if (t < 256) incl[t] += v;
        __syncthreads();
    }
    if (t < 256) { int o = incl[t] - hist[t]; offa[t] = o; cur[t] = o; }
    __syncthreads();
    // phase 3: scatter (single gbuf pass)
    for (int idx = t; idx < cnt; idx += 1024) {
        int pk = gbuf[base + idx];
        sorted[atomicAdd(&cur[pk >> 17], 1)] = pk;
    }
    __syncthreads();
    // phase 4: per-node accumulate (4 threads/node, 2-edge ILP) + transform
    int nl = t >> 2, q = t & 3;
    int node = (b << 8) + nl;
    bool valid = node < N_;
    int my_start = offa[nl], my_cnt = hist[nl];
    const uint4* xr4 = (const uint4*)xh;
    float acc[D_];
#pragma unroll
    for (int j = 0; j < D_; j++) acc[j] = 0.f;
    int i = q;
    for (; i + 4 < my_cnt; i += 8) {          // 2 edges per iter (stride 4 each)
        int p0 = sorted[my_start + i];
        int p1 = sorted[my_start + i + 4];
        size_t r0 = (size_t)(p0 & 131071) * 2;
        size_t r1 = (size_t)(p1 & 131071) * 2;
        uint4 A0 = xr4[r0], B0 = xr4[r0 + 1];
        uint4 A1 = xr4[r1], B1 = xr4[r1 + 1];
        {
            float2 f0 = h2f(A0.x), f1 = h2f(A0.y), f2 = h2f(A0.z);
            float2 f3 = h2f(A0.w), f4 = h2f(B0.x), f5 = h2f(B0.y);
            float w = f5.y;
            acc[0]  = fmaf(w, f0.x, acc[0]);
            acc[1]  = fmaf(w, f0.y, acc[1]);
            acc[2]  = fmaf(w, f1.x, acc[2]);
            acc[3]  = fmaf(w, f1.y, acc[3]);
            acc[4]  = fmaf(w, f2.x, acc[4]);
            acc[5]  = fmaf(w, f2.y, acc[5]);
            acc[6]  = fmaf(w, f3.x, acc[6]);
            acc[7]  = fmaf(w, f3.y, acc[7]);
            acc[8]  = fmaf(w, f4.x, acc[8]);
            acc[9]  = fmaf(w, f4.y, acc[9]);
            acc[10] = fmaf(w, f5.x, acc[10]);
        }
        {
            float2 f0 = h2f(A1.x), f1 = h2f(A1.y), f2 = h2f(A1.z);
            float2 f3 = h2f(A1.w), f4 = h2f(B1.x), f5 = h2f(B1.y);
            float w = f5.y;
            acc[0]  = fmaf(w, f0.x, acc[0]);
            acc[1]  = fmaf(w, f0.y, acc[1]);
            acc[2]  = fmaf(w, f1.x, acc[2]);
            acc[3]  = fmaf(w, f1.y, acc[3]);
            acc[4]  = fmaf(w, f2.x, acc[4]);
            acc[5]  = fmaf(w, f2.y, acc[5]);
            acc[6]  = fmaf(w, f3.x, acc[6]);
            acc[7]  = fmaf(w, f3.y, acc[7]);
            acc[8]  = fmaf(w, f4.x, acc[8]);
            acc[9]  = fmaf(w, f4.y, acc[9]);
            acc[10] = fmaf(w, f5.x, acc[10]);
        }
    }
    for (; i < my_cnt; i += 4) {              // tail (<2 edges for this lane)
        int pack = sorted[my_start + i];
        size_t r = (size_t)(pack & 131071) * 2;
        uint4 A = xr4[r], B = xr4[r + 1];
        float2 f0 = h2f(A.x), f1 = h2f(A.y), f2 = h2f(A.z);
        float2 f3 = h2f(A.w), f4 = h2f(B.x), f5 = h2f(B.y);
        float w = f5.y;
        acc[0]  = fmaf(w, f0.x, acc[0]);
        acc[1]  = fmaf(w, f0.y, acc[1]);
        acc[2]  = fmaf(w, f1.x, acc[2]);
        acc[3]  = fmaf(w, f1.y, acc[3]);
        acc[4]  = fmaf(w, f2.x, acc[4]);
        acc[5]  = fmaf(w, f2.y, acc[5]);
        acc[6]  = fmaf(w, f3.x, acc[6]);
        acc[7]  = fmaf(w, f3.y, acc[7]);
        acc[8]  = fmaf(w, f4.x, acc[8]);
        acc[9]  = fmaf(w, f4.y, acc[9]);
        acc[10] = fmaf(w, f5.x, acc[10]);
    }
#pragma unroll
    for (int j = 0; j < D_; j++) {
        acc[j] += __shfl_xor(acc[j], 1);
        acc[j] += __shfl_xor(acc[j], 2);
    }
    float hreg[16];
    float h2v = 0.f;
    float di = 0.f;
    if (valid) {
        di = rsqrtf((float)(hist[nl] + 1));   // == dis[node], recomputed
        float xr_[D_], g[D_];
#pragma unroll
        for (int j = 0; j < D_; j++) xr_[j] = x[(size_t)node * D_ + j];
        if (q == 0) {
#pragma unroll
            for (int jj = 0; jj < D_; jj++) h2v = fmaf(xr_[jj], sW2[64 + jj], h2v);
        }
#pragma unroll
        for (int j = 0; j < D_; j++) g[j] = di * (acc[j] + di * xr_[j]);
        int fbase = q << 4;
#pragma unroll
        for (int j = 0; j < 16; j++) {
            int f = fbase + j;
            float a = sb1[f];
#pragma unroll
            for (int jj = 0; jj < D_; jj++) a = fmaf(g[jj], sW1[jj * 64 + f], a);
            float hf = fmaxf(a, 0.f);
            hreg[j] = hf;
            h2v = fmaf(hf, sW2[f], h2v);
        }
    } else {
#pragma unroll
        for (int j = 0; j < 16; j++) hreg[j] = 0.f;
    }
    h2v += __shfl_xor(h2v, 1);
    h2v += __shfl_xor(h2v, 2);
    if (valid && q == 0) hd[node] = di * h2v;  // pre-scaled for conv2

    // smean: reduce each feature across the 16 same-quarter lanes (stride 4)
    int lane = t & 63;
#pragma unroll
    for (int j = 0; j < 16; j++) {
        float v = hreg[j];
        v += __shfl_xor(v, 4);
        v += __shfl_xor(v, 8);
        v += __shfl_xor(v, 16);
        v += __shfl_xor(v, 32);
        if (lane < 4) atomicAdd(&smean[(lane << 4) + j], v);
    }
    __syncthreads();
    if (t < 64) atomicAdd(&xpart[((b & (XC_ - 1)) << 6) + t], smean[t]);

    // ready-edge extraction: quad-cooperative
    if (valid && my_cnt > 0 && flag[node]) {
        int r = b & 31;
        int slot = 0;
        if (q == 0) slot = atomicAdd(&rcntp[r * RSTRIDE_], my_cnt);
        slot = __shfl(slot, lane & ~3);
        int lim = min(my_cnt, max(0, RSEG_ - slot));
        for (int i2 = q; i2 < lim; i2 += 4)
            redge[(r << 12) + slot + i2] =
                make_int2(node, sorted[my_start + i2] & 131071);
    }
}

// ---------------- conv2: process the compact ready-edge list ----------------
__global__ void k_pr(const int* __restrict__ rcntp, const int2* __restrict__ redge,
                     const float* __restrict__ hd, float* __restrict__ pr_raw) {
    int idx = blockIdx.x * blockDim.x + threadIdx.x;
    int r = idx >> 12;            // region
    int off = idx & (RSEG_ - 1);
    if (r < 32 && off < min(rcntp[r * RSTRIDE_], RSEG_)) {
        int2 e = redge[(r << 12) + off];
        atomicAdd(&pr_raw[e.x], hd[e.y]);
    }
}

// ---------------- finalize: logits, prob_nothing, v, softmax ----------------
__global__ __launch_bounds__(1024) void k_final(
    const int* __restrict__ ready, const float* __restrict__ dis,
    const float* __restrict__ hd, const float* __restrict__ pr_raw,
    const float* __restrict__ xpart,
    const float* __restrict__ b2,
    const float* __restrict__ Wd, const float* __restrict__ bd,
    const float* __restrict__ Wv, const float* __restrict__ bv,
    float* __restrict__ out) {
    __shared__ float xm[64];
    __shared__ float red[1024];
    __shared__ float s_max, s_sum, s_pn, s_v;
    int t = threadIdx.x;
    if (t < 64) {
        float s = 0.f;
#pragma unroll
        for (int c = 0; c < XC_; c++) s += xpart[(c << 6) + t];
        xm[t] = s * (1.0f / N_);
    }
    __syncthreads();
    if (t == 0) {
        float pn = bd[0], vv = bv[0];
        for (int f = 0; f < 64; f++) { pn += xm[f] * Wd[f]; vv += xm[f] * Wv[f]; }
        s_pn = pn; s_v = vv;
    }
    int r = ready[t];
    float dr = dis[r];
    float l = dr * (pr_raw[r] + hd[r]) + b2[0];   // dr*Σhd[d] + dr²h2[r] + b2
    __syncthreads();
    float pn = s_pn;
    red[t] = (t == 0) ? fmaxf(l, pn) : l;
    __syncthreads();
    for (int sft = 512; sft > 0; sft >>= 1) {
        if (t < sft) red[t] = fmaxf(red[t], red[t + sft]);
        __syncthreads();
    }
    if (t == 0) s_max = red[0];
    __syncthreads();
    float m = s_max;
    float el = expf(l - m);
    red[t] = el + ((t == 0) ? expf(pn - m) : 0.f);
    __syncthreads();
    for (int sft = 512; sft > 0; sft >>= 1) {
        if (t < sft) red[t] += red[t + sft];
        __syncthreads();
    }
    if (t == 0) s_sum = red[0];
    __syncthreads();
    float inv = 1.0f / s_sum;
    out[t] = el * inv;
    if (t == 0) {
        out[K_] = expf(pn - m) * inv;   // prob_nothing slot
        out[K_ + 1] = s_v;              // v
    }
}

extern "C" void kernel_launch(void* const* d_in, const int* in_sizes, int n_in,
                              void* d_out, int out_size, void* d_ws, size_t ws_size,
                              hipStream_t stream) {
    const float* x    = (const float*)d_in[0];
    const int*   ei   = (const int*)d_in[1];
    const int*   src  = ei;
    const int*   dst  = ei + E_;
    const int*   ready= (const int*)d_in[2];
    const float* W1   = (const float*)d_in[3];
    const float* b1   = (const float*)d_in[4];
    const float* W2   = (const float*)d_in[5];
    const float* b2   = (const float*)d_in[6];
    const float* Wd   = (const float*)d_in[7];
    const float* bd   = (const float*)d_in[8];
    const float* Wv   = (const float*)d_in[9];
    const float* bv   = (const float*)d_in[10];
    float* out = (float*)d_out;

    char* ws = (char*)d_ws;
    size_t o = 0;
    int*   bcur   = (int*)(ws + o);          o += align512(NBUCK_ * sizeof(int));
    int*   rcntp  = (int*)(ws + o);          o += align512(32 * RSTRIDE_ * sizeof(int));
    int*   gbuf   = (int*)(ws + o);          o += align512((size_t)NBUCK_ * CAPB_ * sizeof(int));
    int*   ghist  = (int*)(ws + o);          o += align512((size_t)NBUCK_ * 256 * sizeof(int));
    __half* xh    = (__half*)(ws + o);       o += align512((size_t)N_ * 16 * sizeof(__half));
    int2*  redge  = (int2*)(ws + o);         o += align512((size_t)32 * RSEG_ * sizeof(int2));
    float* dis    = (float*)(ws + o);        o += align512(N_ * sizeof(float));
    float* hd     = (float*)(ws + o);        o += align512(N_ * sizeof(float));
    float* pr_raw = (float*)(ws + o);        o += align512(N_ * sizeof(float));
    unsigned char* flag = (unsigned char*)(ws + o); o += align512(N_);
    float* xpart  = (float*)(ws + o);        o += align512(XC_ * 64 * sizeof(float));

    const int B = 256;
    int g_pr = (32 * RSEG_) / B;

    hipMemsetAsync(bcur, 0, NBUCK_ * sizeof(int), stream);
    k_bin  <<<GB_, BT_, 0, stream>>>(src, dst, x, ready, bcur, gbuf,
                                     xh, flag, pr_raw, xpart, rcntp);
    k_deg  <<<NBUCK_, 1024, 0, stream>>>(bcur, gbuf, dis, xh, ghist);
    k_agx  <<<NBUCK_, 1024, 0, stream>>>(bcur, gbuf, ghist, xh, x, flag,
                                         W1, b1, W2, hd, xpart, rcntp, redge);
    k_pr   <<<g_pr, B, 0, stream>>>(rcntp, redge, hd, pr_raw);
    k_final<<<1, 1024, 0, stream>>>(ready, dis, hd, pr_raw, xpart,
                                    b2, Wd, bd, Wv, bv, out);
}